// Round 4
// baseline (2915.838 us; speedup 1.0000x reference)
//
#include <hip/hip_runtime.h>
#include <math.h>

// Force numpy-style arithmetic everywhere: no FMA contraction, no reassociation.
#pragma clang fp contract(off)
#pragma clang fp reassociate(off)

#define NU 100000
#define NI 50000
#define NT 150000
#define DD 64
#define NE 2000000
#define NTD (NT * DD)

__global__ __launch_bounds__(256) void zero_k(int* __restrict__ p, int n) {
  int i = blockIdx.x * 256 + threadIdx.x;
  if (i < n) p[i] = 0;
}

__global__ __launch_bounds__(256) void count_k(const int* __restrict__ eu, const int* __restrict__ ei,
                                               int* __restrict__ cnt) {
  int idx = blockIdx.x * blockDim.x + threadIdx.x;
  int stride = gridDim.x * blockDim.x;
  for (int e = idx; e < NE; e += stride) {
    atomicAdd(&cnt[eu[e]], 1);
    atomicAdd(&cnt[NU + ei[e]], 1);
  }
}

__global__ __launch_bounds__(1024) void scanA_k(const int* __restrict__ cnt, int* __restrict__ lexcl,
                                                int* __restrict__ partials, int n) {
  int idx = blockIdx.x * 1024 + threadIdx.x;
  int v = (idx < n) ? cnt[idx] : 0;
  int lane = threadIdx.x & 63;
  int wid = threadIdx.x >> 6;
  int x = v;
#pragma unroll
  for (int off = 1; off < 64; off <<= 1) {
    int y = __shfl_up(x, off, 64);
    if (lane >= off) x += y;
  }
  __shared__ int wtot[16], woff[16];
  if (lane == 63) wtot[wid] = x;
  __syncthreads();
  if (threadIdx.x == 0) {
    int a = 0;
#pragma unroll
    for (int w = 0; w < 16; ++w) { woff[w] = a; a += wtot[w]; }
    partials[blockIdx.x] = a;
  }
  __syncthreads();
  if (idx < n) lexcl[idx] = x - v + woff[wid];
}

__global__ __launch_bounds__(64) void scanB_k(int* __restrict__ partials, int* __restrict__ row, int nchunks) {
  int lane = threadIdx.x;
  int carry = 0;
  for (int base = 0; base < nchunks; base += 64) {
    int idx = base + lane;
    int v = (idx < nchunks) ? partials[idx] : 0;
    int x = v;
#pragma unroll
    for (int off = 1; off < 64; off <<= 1) {
      int y = __shfl_up(x, off, 64);
      if (lane >= off) x += y;
    }
    if (idx < nchunks) partials[idx] = carry + x - v;
    carry += __shfl(x, 63, 64);
  }
  if (lane == 0) row[NT] = carry;
}

__global__ __launch_bounds__(1024) void scanC_k(int* __restrict__ row, int* __restrict__ cursor,
                                                float* __restrict__ coef, const int* __restrict__ partials, int n) {
  int idx = blockIdx.x * 1024 + threadIdx.x;
  if (idx >= n) return;
  int c = cursor[idx];  // raw count
  int fin = row[idx] + partials[blockIdx.x];
  row[idx] = fin;
  cursor[idx] = fin;
  coef[idx] = (float)pow((double)(c > 0 ? c : 1), -0.5);  // matches CR powf
}

__global__ __launch_bounds__(256) void fill_k(const int* __restrict__ eu, const int* __restrict__ ei,
                                              int* __restrict__ cursor, int* __restrict__ eid) {
  int idx = blockIdx.x * blockDim.x + threadIdx.x;
  int stride = gridDim.x * blockDim.x;
  for (int e = idx; e < NE; e += stride) {
    int u = eu[e], it = ei[e];
    int pu = atomicAdd(&cursor[u], 1);
    eid[pu] = e;
    int pi = atomicAdd(&cursor[NU + it], 1);
    eid[pi] = e;
  }
}

// Rank-sort each segment by edge id (distinct within a segment) -> col/seid in exact edge order.
__global__ __launch_bounds__(256) void sort_k(const int* __restrict__ row, const int* __restrict__ eid,
                                              const int* __restrict__ eu, const int* __restrict__ ei,
                                              int* __restrict__ col, int* __restrict__ seid) {
  int wv = (blockIdx.x * blockDim.x + threadIdx.x) >> 6;
  int lane = threadIdx.x & 63;
  if (wv >= NT) return;
  int beg = row[wv], end = row[wv + 1];
  for (int idx = beg + lane; idx < end; idx += 64) {
    int my = eid[idx];
    int r = 0;
    for (int j = beg; j < end; ++j) r += (eid[j] < my);
    col[beg + r] = (wv < NU) ? (NU + ei[my]) : eu[my];
    seid[beg + r] = my;
  }
}

// CSR integrity checks -> flag bits (deterministic).
__global__ __launch_bounds__(256) void verify_k(const int* __restrict__ row, const int* __restrict__ cursor,
                                                const int* __restrict__ col, const int* __restrict__ seid,
                                                int* __restrict__ flag) {
  int wv = (blockIdx.x * blockDim.x + threadIdx.x) >> 6;
  int lane = threadIdx.x & 63;
  if (wv >= NT) return;
  if (wv == 0 && lane == 0 && row[NT] != 2 * NE) atomicOr(flag, 1);
  if (lane == 0 && cursor[wv] != row[wv + 1]) atomicOr(flag, 2);
  int beg = row[wv], end = row[wv + 1];
  for (int idx = beg + lane; idx < end; idx += 64) {
    int c = col[idx];
    bool bad = (wv < NU) ? (c < NU || c >= NT) : (c < 0 || c >= NU);
    if (bad) atomicOr(flag, 4);
    if (idx > beg && seid[idx] <= seid[idx - 1]) atomicOr(flag, 8);
  }
}

__global__ void poison_k(const int* __restrict__ flag, float* __restrict__ out) {
  int f = flag[0];
  if (f != 0 && threadIdx.x < 64) out[threadIdx.x] = 1.0e9f * (float)(1 + f);
}

__global__ __launch_bounds__(256) void init_k(const float* __restrict__ ue, const float* __restrict__ ie,
                                              float* __restrict__ emb, float* __restrict__ acc) {
  int idx = blockIdx.x * blockDim.x + threadIdx.x;
  int stride = gridDim.x * blockDim.x;
  for (int j = idx; j < NTD; j += stride) {
    float v = (j < NU * DD) ? ue[j] : ie[j - NU * DD];
    emb[j] = v;
    acc[j] = v;
  }
}

// GCN layer bit-replicating np.add.at: f32, strict edge order, separate mul/add rounding (pragmas above).
__global__ __launch_bounds__(256) void gcn_seq_k(const float* __restrict__ in, float* __restrict__ out,
                                                 float* __restrict__ acc,
                                                 const int* __restrict__ row, const int* __restrict__ col,
                                                 const float* __restrict__ coef, const float* __restrict__ nz_l) {
  int wv = (blockIdx.x * blockDim.x + threadIdx.x) >> 6;
  int lane = threadIdx.x & 63;
  if (wv >= NT) return;
  int beg = row[wv], end = row[wv + 1];
  float cn = coef[wv];
  float s = 0.f;
  for (int k = beg; k < end; ++k) {
    int m = col[k];
    float w = cn * coef[m];         // np: cu[edge_u]*ci[edge_i], one rounding
    float t = in[m * DD + lane] * w; // np: ie_g * w, one rounding
    s = s + t;                       // np: add.at sequential, one rounding
  }
  // Noise norm: replicate numpy pairwise_sum(n=64): 8 accumulators + fixed tree.
  float nz = nz_l[wv * DD + lane];
  float sq = nz * nz;
  float r[8];
#pragma unroll
  for (int j = 0; j < 8; ++j) r[j] = __shfl(sq, j, 64);
#pragma unroll
  for (int k = 1; k < 8; ++k) {
#pragma unroll
    for (int j = 0; j < 8; ++j) r[j] = r[j] + __shfl(sq, 8 * k + j, 64);
  }
  float t01 = r[0] + r[1], t23 = r[2] + r[3];
  float t45 = r[4] + r[5], t67 = r[6] + r[7];
  float tot = (t01 + t23) + (t45 + t67);
  float nrm = __fsqrt_rn(tot);
  float den = fmaxf(nrm, 1e-12f);
  float nn = nz / den;
  float sgn = (s > 0.f) ? 1.f : ((s < 0.f) ? -1.f : 0.f);
  float o = s + ((sgn * nn) * 0.2f);
  int base = wv * DD + lane;
  out[base] = o;
  acc[base] = acc[base] + o;  // ((e0+e1)+e2)+e3 sequential across layers
}

__global__ __launch_bounds__(256) void mean_k(const float* __restrict__ acc, float* __restrict__ emb) {
  int idx = blockIdx.x * blockDim.x + threadIdx.x;
  int stride = gridDim.x * blockDim.x;
  for (int j = idx; j < NTD; j += stride) emb[j] = acc[j] * 0.25f;
}

// Rankformer layer (smooth ops; exact rounding not required).
__global__ __launch_bounds__(256) void rf_k(const float* __restrict__ in, float* __restrict__ out,
                                            const int* __restrict__ row, const int* __restrict__ col) {
  int wv = (blockIdx.x * blockDim.x + threadIdx.x) >> 6;
  int lane = threadIdx.x & 63;
  if (wv >= NT) return;
  int beg = row[wv], end = row[wv + 1];
  float e = in[wv * DD + lane];
  float m = -__builtin_inff(), z = 0.f, r = 0.f;
  for (int k = beg; k < end; ++k) {
    int mm = col[k];
    float v = in[mm * DD + lane];
    float d = e * v;
#pragma unroll
    for (int off = 1; off < 64; off <<= 1) d += __shfl_xor(d, off, 64);
    float nm = fmaxf(m, d);
    float sc = expf(m - nm);
    float p = expf(d - nm);
    z = z * sc + p;
    r = r * sc + p * v;
    m = nm;
  }
  float rec = r / fmaxf(z, 1e-9f);
  out[wv * DD + lane] = 0.5f * e + 0.5f * rec;
}

extern "C" void kernel_launch(void* const* d_in, const int* in_sizes, int n_in,
                              void* d_out, int out_size, void* d_ws, size_t ws_size,
                              hipStream_t stream) {
  const float* user_emb = (const float*)d_in[0];
  const float* item_emb = (const float*)d_in[1];
  const float* noise    = (const float*)d_in[2];
  const int*   edge_u   = (const int*)d_in[3];
  const int*   edge_i   = (const int*)d_in[4];
  float* out = (float*)d_out;

  // ws layout (~127 MB)
  float* embA = (float*)d_ws;                      // NTD
  float* embB = embA + (size_t)NTD;                // NTD
  float* coef = embB + (size_t)NTD;                // NT+16
  int*   row  = (int*)(coef + (NT + 16));          // NT+16
  int*   cursor = row + (NT + 16);                 // NT+16
  int*   partials = cursor + (NT + 16);            // 256
  int*   flag = partials + 256;                    // 16
  int*   eidt = flag + 16;                         // 2E
  int*   col  = eidt + 2 * (size_t)NE;             // 2E
  int*   seid = col + 2 * (size_t)NE;              // 2E

  float* acc = out;  // layer-mean accumulator lives in d_out until the final RF pass

  const int nchunks = (NT + 1023) / 1024;

  zero_k<<<(NT + 255) / 256, 256, 0, stream>>>(cursor, NT);
  zero_k<<<1, 256, 0, stream>>>(flag, 16);
  count_k<<<1024, 256, 0, stream>>>(edge_u, edge_i, cursor);
  scanA_k<<<nchunks, 1024, 0, stream>>>(cursor, row, partials, NT);
  scanB_k<<<1, 64, 0, stream>>>(partials, row, nchunks);
  scanC_k<<<nchunks, 1024, 0, stream>>>(row, cursor, coef, partials, NT);
  fill_k<<<1024, 256, 0, stream>>>(edge_u, edge_i, cursor, eidt);

  const int gwave = (NT * 64 + 255) / 256;  // one wave per node
  sort_k<<<gwave, 256, 0, stream>>>(row, eidt, edge_u, edge_i, col, seid);
  verify_k<<<gwave, 256, 0, stream>>>(row, cursor, col, seid, flag);
  init_k<<<4096, 256, 0, stream>>>(user_emb, item_emb, embA, acc);

  float* cur = embA;
  float* nxt = embB;
  for (int layer = 0; layer < 3; ++layer) {
    gcn_seq_k<<<gwave, 256, 0, stream>>>(cur, nxt, acc, row, col, coef,
                                         noise + (size_t)layer * NTD);
    float* t = cur; cur = nxt; nxt = t;
  }
  mean_k<<<4096, 256, 0, stream>>>(acc, embA);
  rf_k<<<gwave, 256, 0, stream>>>(embA, embB, row, col);
  rf_k<<<gwave, 256, 0, stream>>>(embB, out, row, col);
  poison_k<<<1, 64, 0, stream>>>(flag, out);
}

// Round 5
// 1871.328 us; speedup vs baseline: 1.5582x; 1.5582x over previous
//
#include <hip/hip_runtime.h>
#include <math.h>

// Force numpy-style arithmetic: no FMA contraction, no reassociation.
// RF kernels use explicit fmaf() where fusion is wanted (smooth ops).
#pragma clang fp contract(off)
#pragma clang fp reassociate(off)

#define NU 100000
#define NI 50000
#define NT 150000
#define DD 64
#define NE 2000000
#define NTD (NT * DD)

__global__ __launch_bounds__(256) void zero_k(int* __restrict__ p, int n) {
  int i = blockIdx.x * 256 + threadIdx.x;
  if (i < n) p[i] = 0;
}

__global__ __launch_bounds__(256) void count_k(const int* __restrict__ eu, const int* __restrict__ ei,
                                               int* __restrict__ cnt) {
  int idx = blockIdx.x * blockDim.x + threadIdx.x;
  int stride = gridDim.x * blockDim.x;
  for (int e = idx; e < NE; e += stride) {
    atomicAdd(&cnt[eu[e]], 1);
    atomicAdd(&cnt[NU + ei[e]], 1);
  }
}

__global__ __launch_bounds__(1024) void scanA_k(const int* __restrict__ cnt, int* __restrict__ lexcl,
                                                int* __restrict__ partials, int n) {
  int idx = blockIdx.x * 1024 + threadIdx.x;
  int v = (idx < n) ? cnt[idx] : 0;
  int lane = threadIdx.x & 63;
  int wid = threadIdx.x >> 6;
  int x = v;
#pragma unroll
  for (int off = 1; off < 64; off <<= 1) {
    int y = __shfl_up(x, off, 64);
    if (lane >= off) x += y;
  }
  __shared__ int wtot[16], woff[16];
  if (lane == 63) wtot[wid] = x;
  __syncthreads();
  if (threadIdx.x == 0) {
    int a = 0;
#pragma unroll
    for (int w = 0; w < 16; ++w) { woff[w] = a; a += wtot[w]; }
    partials[blockIdx.x] = a;
  }
  __syncthreads();
  if (idx < n) lexcl[idx] = x - v + woff[wid];
}

__global__ __launch_bounds__(64) void scanB_k(int* __restrict__ partials, int* __restrict__ row, int nchunks) {
  int lane = threadIdx.x;
  int carry = 0;
  for (int base = 0; base < nchunks; base += 64) {
    int idx = base + lane;
    int v = (idx < nchunks) ? partials[idx] : 0;
    int x = v;
#pragma unroll
    for (int off = 1; off < 64; off <<= 1) {
      int y = __shfl_up(x, off, 64);
      if (lane >= off) x += y;
    }
    if (idx < nchunks) partials[idx] = carry + x - v;
    carry += __shfl(x, 63, 64);
  }
  if (lane == 0) row[NT] = carry;
}

__global__ __launch_bounds__(1024) void scanC_k(int* __restrict__ row, int* __restrict__ cursor,
                                                float* __restrict__ coef, const int* __restrict__ partials, int n) {
  int idx = blockIdx.x * 1024 + threadIdx.x;
  if (idx >= n) return;
  int c = cursor[idx];  // raw count
  int fin = row[idx] + partials[blockIdx.x];
  row[idx] = fin;
  cursor[idx] = fin;
  coef[idx] = (float)pow((double)(c > 0 ? c : 1), -0.5);
}

__global__ __launch_bounds__(256) void fill_k(const int* __restrict__ eu, const int* __restrict__ ei,
                                              int* __restrict__ cursor, int* __restrict__ eid) {
  int idx = blockIdx.x * blockDim.x + threadIdx.x;
  int stride = gridDim.x * blockDim.x;
  for (int e = idx; e < NE; e += stride) {
    int u = eu[e], it = ei[e];
    int pu = atomicAdd(&cursor[u], 1);
    eid[pu] = e;
    int pi = atomicAdd(&cursor[NU + it], 1);
    eid[pi] = e;
  }
}

// Rank-sort each segment by edge id -> col/seid in exact edge order (deterministic).
__global__ __launch_bounds__(256) void sort_k(const int* __restrict__ row, const int* __restrict__ eid,
                                              const int* __restrict__ eu, const int* __restrict__ ei,
                                              int* __restrict__ col, int* __restrict__ seid) {
  int wv = (blockIdx.x * blockDim.x + threadIdx.x) >> 6;
  int lane = threadIdx.x & 63;
  if (wv >= NT) return;
  int beg = row[wv], end = row[wv + 1];
  for (int idx = beg + lane; idx < end; idx += 64) {
    int my = eid[idx];
    int r = 0;
    for (int j = beg; j < end; ++j) r += (eid[j] < my);
    col[beg + r] = (wv < NU) ? (NU + ei[my]) : eu[my];
    seid[beg + r] = my;
  }
}

__global__ __launch_bounds__(256) void init_k(const float* __restrict__ ue, const float* __restrict__ ie,
                                              float* __restrict__ emb, float* __restrict__ acc) {
  int idx = blockIdx.x * blockDim.x + threadIdx.x;
  int stride = gridDim.x * blockDim.x;
  for (int j = idx; j < NTD; j += stride) {
    float v = (j < NU * DD) ? ue[j] : ie[j - NU * DD];
    emb[j] = v;
    acc[j] = v;
  }
}

// GCN layer: 4 nodes/wave, 16 lanes x float4 dims. Bit-identical arithmetic to the
// validated 64-lane version: per-dim strict edge-order sum, separate mul/add rounding,
// noise pairwise-sum r[j]=sum_k sq[8k+j] sequential in k + fixed tree.
__global__ __launch_bounds__(256) void gcn4_k(const float* __restrict__ in, float* __restrict__ out,
                                              float* __restrict__ acc,
                                              const int* __restrict__ row, const int* __restrict__ col,
                                              const float* __restrict__ coef, const float* __restrict__ nz_l) {
  int wave = (blockIdx.x * blockDim.x + threadIdx.x) >> 6;
  int lane = threadIdx.x & 63;
  int g = lane >> 4, q = lane & 15;
  int node = wave * 4 + g;
  if (node >= NT) return;
  int beg = row[node], end = row[node + 1];
  float cn = coef[node];
  float sx = 0.f, sy = 0.f, sz = 0.f, sw = 0.f;
  for (int k = beg; k < end; ++k) {
    int m = col[k];
    float w = cn * coef[m];                                   // one rounding (np: cu*ci)
    float4 v = *(const float4*)(in + (size_t)m * DD + q * 4);
    sx = sx + (v.x * w);                                      // mul then add, per-op rounding
    sy = sy + (v.y * w);
    sz = sz + (v.z * w);
    sw = sw + (v.w * w);
  }
  // Noise norm, bit-identical: r[j] = sum over k of sq[8k+j] (sequential), tree combine.
  float4 nzv = *(const float4*)(nz_l + (size_t)node * DD + q * 4);
  float4 sq;
  sq.x = nzv.x * nzv.x; sq.y = nzv.y * nzv.y;
  sq.z = nzv.z * nzv.z; sq.w = nzv.w * nzv.w;
  // lane (base + 2k) holds dims {8k..8k+3} -> r[0..3]; lane (base + 2k+1) holds {8k+4..8k+7} -> r[4..7]
  float rA0 = 0.f, rA1 = 0.f, rA2 = 0.f, rA3 = 0.f;
  float rB0 = 0.f, rB1 = 0.f, rB2 = 0.f, rB3 = 0.f;
  int base = g * 16;
#pragma unroll
  for (int k = 0; k < 8; ++k) {
    int le = base + 2 * k, lo = le + 1;
    rA0 = rA0 + __shfl(sq.x, le, 64);
    rA1 = rA1 + __shfl(sq.y, le, 64);
    rA2 = rA2 + __shfl(sq.z, le, 64);
    rA3 = rA3 + __shfl(sq.w, le, 64);
    rB0 = rB0 + __shfl(sq.x, lo, 64);
    rB1 = rB1 + __shfl(sq.y, lo, 64);
    rB2 = rB2 + __shfl(sq.z, lo, 64);
    rB3 = rB3 + __shfl(sq.w, lo, 64);
  }
  float t01 = rA0 + rA1, t23 = rA2 + rA3;
  float t45 = rB0 + rB1, t67 = rB2 + rB3;
  float tot = (t01 + t23) + (t45 + t67);
  float nrm = __fsqrt_rn(tot);
  float den = fmaxf(nrm, 1e-12f);
  float4 o;
  {
    float nn = nzv.x / den;
    float sg = (sx > 0.f) ? 1.f : ((sx < 0.f) ? -1.f : 0.f);
    o.x = sx + ((sg * nn) * 0.2f);
  }
  {
    float nn = nzv.y / den;
    float sg = (sy > 0.f) ? 1.f : ((sy < 0.f) ? -1.f : 0.f);
    o.y = sy + ((sg * nn) * 0.2f);
  }
  {
    float nn = nzv.z / den;
    float sg = (sz > 0.f) ? 1.f : ((sz < 0.f) ? -1.f : 0.f);
    o.z = sz + ((sg * nn) * 0.2f);
  }
  {
    float nn = nzv.w / den;
    float sg = (sw > 0.f) ? 1.f : ((sw < 0.f) ? -1.f : 0.f);
    o.w = sw + ((sg * nn) * 0.2f);
  }
  size_t boff = (size_t)node * DD + q * 4;
  *(float4*)(out + boff) = o;
  float4 a = *(const float4*)(acc + boff);
  a.x = a.x + o.x; a.y = a.y + o.y; a.z = a.z + o.z; a.w = a.w + o.w;
  *(float4*)(acc + boff) = a;
}

__global__ __launch_bounds__(256) void mean_k(const float* __restrict__ acc, float* __restrict__ emb) {
  int idx = blockIdx.x * blockDim.x + threadIdx.x;
  int stride = gridDim.x * blockDim.x;
  for (int j = idx; j < NTD; j += stride) emb[j] = acc[j] * 0.25f;
}

// RF phase 1: s[e] = dot(emb_u, emb_i) once per edge. 4 edges/wave, 16 lanes x float4.
__global__ __launch_bounds__(256) void score_k(const float* __restrict__ emb,
                                               const int* __restrict__ eu, const int* __restrict__ ei,
                                               float* __restrict__ S) {
  int wave = (blockIdx.x * blockDim.x + threadIdx.x) >> 6;
  int lane = threadIdx.x & 63;
  int g = lane >> 4, q = lane & 15;
  int e = wave * 4 + g;
  if (e >= NE) return;
  int u = eu[e];
  int it = NU + ei[e];
  float4 a = *(const float4*)(emb + (size_t)u * DD + q * 4);
  float4 b = *(const float4*)(emb + (size_t)it * DD + q * 4);
  float d = fmaf(a.x, b.x, fmaf(a.y, b.y, fmaf(a.z, b.z, a.w * b.w)));
#pragma unroll
  for (int off = 1; off < 16; off <<= 1) d += __shfl_xor(d, off, 64);
  if (q == 0) S[e] = d;
}

// RF phase 2: per node, m = max s, p[k] = exp(s-m) (unnormalized, CSR order), Zinv = 1/max(sum p,1e-9).
__global__ __launch_bounds__(256) void mz_k(const float* __restrict__ S,
                                            const int* __restrict__ row, const int* __restrict__ seid,
                                            float* __restrict__ P, float* __restrict__ Zinv) {
  int wv = (blockIdx.x * blockDim.x + threadIdx.x) >> 6;
  int lane = threadIdx.x & 63;
  if (wv >= NT) return;
  int beg = row[wv], end = row[wv + 1];
  int n0 = beg + lane;
  float s0 = 0.f;
  float m = -__builtin_inff();
  if (n0 < end) { s0 = S[seid[n0]]; m = s0; }
  for (int idx = n0 + 64; idx < end; idx += 64) m = fmaxf(m, S[seid[idx]]);
#pragma unroll
  for (int off = 1; off < 64; off <<= 1) m = fmaxf(m, __shfl_xor(m, off, 64));
  float zp = 0.f;
  if (n0 < end) { float p = __expf(s0 - m); P[n0] = p; zp = p; }
  for (int idx = n0 + 64; idx < end; idx += 64) {
    float p = __expf(S[seid[idx]] - m);
    P[idx] = p;
    zp += p;
  }
#pragma unroll
  for (int off = 1; off < 64; off <<= 1) zp += __shfl_xor(zp, off, 64);
  if (lane == 0) Zinv[wv] = 1.f / fmaxf(zp, 1e-9f);
}

// RF phase 3: rec = Zinv * sum p*v; out = 0.5*e + 0.5*rec. 4 nodes/wave, 16 lanes x float4.
__global__ __launch_bounds__(256) void accum_k(const float* __restrict__ in, float* __restrict__ out,
                                               const int* __restrict__ row, const int* __restrict__ col,
                                               const float* __restrict__ P, const float* __restrict__ Zinv) {
  int wave = (blockIdx.x * blockDim.x + threadIdx.x) >> 6;
  int lane = threadIdx.x & 63;
  int g = lane >> 4, q = lane & 15;
  int node = wave * 4 + g;
  if (node >= NT) return;
  int beg = row[node], end = row[node + 1];
  float rx = 0.f, ry = 0.f, rz = 0.f, rw = 0.f;
  int k = beg;
  for (; k + 2 <= end; k += 2) {
    float p0 = P[k], p1 = P[k + 1];
    int c0 = col[k], c1 = col[k + 1];
    float4 v0 = *(const float4*)(in + (size_t)c0 * DD + q * 4);
    float4 v1 = *(const float4*)(in + (size_t)c1 * DD + q * 4);
    rx = fmaf(p0, v0.x, rx); ry = fmaf(p0, v0.y, ry);
    rz = fmaf(p0, v0.z, rz); rw = fmaf(p0, v0.w, rw);
    rx = fmaf(p1, v1.x, rx); ry = fmaf(p1, v1.y, ry);
    rz = fmaf(p1, v1.z, rz); rw = fmaf(p1, v1.w, rw);
  }
  for (; k < end; ++k) {
    float p = P[k];
    int c = col[k];
    float4 v = *(const float4*)(in + (size_t)c * DD + q * 4);
    rx = fmaf(p, v.x, rx); ry = fmaf(p, v.y, ry);
    rz = fmaf(p, v.z, rz); rw = fmaf(p, v.w, rw);
  }
  float zi = Zinv[node];
  size_t boff = (size_t)node * DD + q * 4;
  float4 e = *(const float4*)(in + boff);
  float4 o;
  o.x = 0.5f * e.x + 0.5f * (rx * zi);
  o.y = 0.5f * e.y + 0.5f * (ry * zi);
  o.z = 0.5f * e.z + 0.5f * (rz * zi);
  o.w = 0.5f * e.w + 0.5f * (rw * zi);
  *(float4*)(out + boff) = o;
}

extern "C" void kernel_launch(void* const* d_in, const int* in_sizes, int n_in,
                              void* d_out, int out_size, void* d_ws, size_t ws_size,
                              hipStream_t stream) {
  const float* user_emb = (const float*)d_in[0];
  const float* item_emb = (const float*)d_in[1];
  const float* noise    = (const float*)d_in[2];
  const int*   edge_u   = (const int*)d_in[3];
  const int*   edge_i   = (const int*)d_in[4];
  float* out = (float*)d_out;

  // ws layout (~136 MB)
  float* embA = (float*)d_ws;                      // NTD
  float* embB = embA + (size_t)NTD;                // NTD
  float* coef = embB + (size_t)NTD;                // NT+16
  int*   row  = (int*)(coef + (NT + 16));          // NT+16
  int*   cursor = row + (NT + 16);                 // NT+16
  int*   partials = cursor + (NT + 16);            // 256
  int*   eidt = partials + 256;                    // 2E (dead after sort_k -> reused as P)
  int*   col  = eidt + 2 * (size_t)NE;             // 2E
  int*   seid = col + 2 * (size_t)NE;              // 2E
  float* S    = (float*)(seid + 2 * (size_t)NE);   // E
  float* Zinv = S + NE;                            // NT+16
  float* P    = (float*)eidt;                      // 2E (aliases eidt)

  float* acc = out;  // layer-mean accumulator lives in d_out until the final RF pass

  const int nchunks = (NT + 1023) / 1024;

  zero_k<<<(NT + 255) / 256, 256, 0, stream>>>(cursor, NT);
  count_k<<<1024, 256, 0, stream>>>(edge_u, edge_i, cursor);
  scanA_k<<<nchunks, 1024, 0, stream>>>(cursor, row, partials, NT);
  scanB_k<<<1, 64, 0, stream>>>(partials, row, nchunks);
  scanC_k<<<nchunks, 1024, 0, stream>>>(row, cursor, coef, partials, NT);
  fill_k<<<1024, 256, 0, stream>>>(edge_u, edge_i, cursor, eidt);

  const int gwave = (NT * 64 + 255) / 256;   // 64-lane-per-node grids (sort, mz)
  const int g4    = (NT / 4 * 64) / 256;     // 4-node-per-wave grids (gcn4, accum) = 9375
  const int gsc   = (NE / 4 * 64) / 256;     // score grid = 125000

  sort_k<<<gwave, 256, 0, stream>>>(row, eidt, edge_u, edge_i, col, seid);
  init_k<<<4096, 256, 0, stream>>>(user_emb, item_emb, embA, acc);

  float* cur = embA;
  float* nxt = embB;
  for (int layer = 0; layer < 3; ++layer) {
    gcn4_k<<<g4, 256, 0, stream>>>(cur, nxt, acc, row, col, coef,
                                   noise + (size_t)layer * NTD);
    float* t = cur; cur = nxt; nxt = t;
  }
  mean_k<<<4096, 256, 0, stream>>>(acc, embA);

  // RF layer 1: embA -> embB
  score_k<<<gsc, 256, 0, stream>>>(embA, edge_u, edge_i, S);
  mz_k<<<gwave, 256, 0, stream>>>(S, row, seid, P, Zinv);
  accum_k<<<g4, 256, 0, stream>>>(embA, embB, row, col, P, Zinv);
  // RF layer 2: embB -> out
  score_k<<<gsc, 256, 0, stream>>>(embB, edge_u, edge_i, S);
  mz_k<<<gwave, 256, 0, stream>>>(S, row, seid, P, Zinv);
  accum_k<<<g4, 256, 0, stream>>>(embB, out, row, col, P, Zinv);
}

// Round 6
// 1776.485 us; speedup vs baseline: 1.6414x; 1.0534x over previous
//
#include <hip/hip_runtime.h>
#include <math.h>

// Force numpy-style arithmetic: no FMA contraction, no reassociation.
// RF kernels use explicit fmaf() where fusion is wanted (smooth ops).
#pragma clang fp contract(off)
#pragma clang fp reassociate(off)

#define NU 100000
#define NI 50000
#define NT 150000
#define DD 64
#define NE 2000000
#define NTD (NT * DD)
#define NSLICE 12
#define SLICEW (NT / NSLICE)   // 12500

__global__ __launch_bounds__(256) void zero_k(int* __restrict__ p, int n) {
  int i = blockIdx.x * 256 + threadIdx.x;
  if (i < n) p[i] = 0;
}

__global__ __launch_bounds__(256) void count_k(const int* __restrict__ eu, const int* __restrict__ ei,
                                               int* __restrict__ cnt) {
  int idx = blockIdx.x * blockDim.x + threadIdx.x;
  int stride = gridDim.x * blockDim.x;
  for (int e = idx; e < NE; e += stride) {
    atomicAdd(&cnt[eu[e]], 1);
    atomicAdd(&cnt[NU + ei[e]], 1);
  }
}

__global__ __launch_bounds__(1024) void scanA_k(const int* __restrict__ cnt, int* __restrict__ lexcl,
                                                int* __restrict__ partials, int n) {
  int idx = blockIdx.x * 1024 + threadIdx.x;
  int v = (idx < n) ? cnt[idx] : 0;
  int lane = threadIdx.x & 63;
  int wid = threadIdx.x >> 6;
  int x = v;
#pragma unroll
  for (int off = 1; off < 64; off <<= 1) {
    int y = __shfl_up(x, off, 64);
    if (lane >= off) x += y;
  }
  __shared__ int wtot[16], woff[16];
  if (lane == 63) wtot[wid] = x;
  __syncthreads();
  if (threadIdx.x == 0) {
    int a = 0;
#pragma unroll
    for (int w = 0; w < 16; ++w) { woff[w] = a; a += wtot[w]; }
    partials[blockIdx.x] = a;
  }
  __syncthreads();
  if (idx < n) lexcl[idx] = x - v + woff[wid];
}

__global__ __launch_bounds__(64) void scanB_k(int* __restrict__ partials, int* __restrict__ row, int nchunks) {
  int lane = threadIdx.x;
  int carry = 0;
  for (int base = 0; base < nchunks; base += 64) {
    int idx = base + lane;
    int v = (idx < nchunks) ? partials[idx] : 0;
    int x = v;
#pragma unroll
    for (int off = 1; off < 64; off <<= 1) {
      int y = __shfl_up(x, off, 64);
      if (lane >= off) x += y;
    }
    if (idx < nchunks) partials[idx] = carry + x - v;
    carry += __shfl(x, 63, 64);
  }
  if (lane == 0) row[NT] = carry;
}

__global__ __launch_bounds__(1024) void scanC_k(int* __restrict__ row, int* __restrict__ cursor,
                                                float* __restrict__ coef, const int* __restrict__ partials, int n) {
  int idx = blockIdx.x * 1024 + threadIdx.x;
  if (idx >= n) return;
  int c = cursor[idx];  // raw count
  int fin = row[idx] + partials[blockIdx.x];
  row[idx] = fin;
  cursor[idx] = fin;
  coef[idx] = (float)pow((double)(c > 0 ? c : 1), -0.5);
}

// Destination-sliced fill: pass p only writes endpoints whose node is in slice p,
// confining the scatter window (~1.33 MB eid + 50 KB cursor) to L2 residency.
// Edge reads repeat across passes but hit L1/L2. No cross-pass ordering needed.
__global__ __launch_bounds__(256) void fill_k(const int* __restrict__ eu, const int* __restrict__ ei,
                                              int* __restrict__ cursor, int* __restrict__ eid) {
  int idx = blockIdx.x * blockDim.x + threadIdx.x;
  int stride = gridDim.x * blockDim.x;
  for (int pass = 0; pass < NSLICE; ++pass) {
    int lo = pass * SLICEW, hi = lo + SLICEW;
    for (int e = idx; e < NE; e += stride) {
      int u = eu[e];
      int it = NU + ei[e];
      if (u >= lo && u < hi) {
        int p = atomicAdd(&cursor[u], 1);
        eid[p] = e;
      }
      if (it >= lo && it < hi) {
        int p = atomicAdd(&cursor[it], 1);
        eid[p] = e;
      }
    }
  }
}

// Rank-sort each segment by edge id -> col/seid in exact edge order (deterministic).
__global__ __launch_bounds__(256) void sort_k(const int* __restrict__ row, const int* __restrict__ eid,
                                              const int* __restrict__ eu, const int* __restrict__ ei,
                                              int* __restrict__ col, int* __restrict__ seid) {
  int wv = (blockIdx.x * blockDim.x + threadIdx.x) >> 6;
  int lane = threadIdx.x & 63;
  if (wv >= NT) return;
  int beg = row[wv], end = row[wv + 1];
  for (int idx = beg + lane; idx < end; idx += 64) {
    int my = eid[idx];
    int r = 0;
    for (int j = beg; j < end; ++j) r += (eid[j] < my);
    col[beg + r] = (wv < NU) ? (NU + ei[my]) : eu[my];
    seid[beg + r] = my;
  }
}

__global__ __launch_bounds__(256) void init_k(const float* __restrict__ ue, const float* __restrict__ ie,
                                              float* __restrict__ emb, float* __restrict__ acc) {
  int idx = blockIdx.x * blockDim.x + threadIdx.x;
  int stride = gridDim.x * blockDim.x;
  for (int j = idx; j < NTD; j += stride) {
    float v = (j < NU * DD) ? ue[j] : ie[j - NU * DD];
    emb[j] = v;
    acc[j] = v;
  }
}

// GCN layer: 4 nodes/wave, 16 lanes x float4 dims, depth-2 gather pipeline.
// Arithmetic bit-identical to the validated version: per-dim strict edge-order sum,
// separate mul/add rounding; noise pairwise-sum r[j]=sum_k sq[8k+j] + fixed tree.
__global__ __launch_bounds__(256) void gcn4_k(const float* __restrict__ in, float* __restrict__ out,
                                              float* __restrict__ acc,
                                              const int* __restrict__ row, const int* __restrict__ col,
                                              const float* __restrict__ coef, const float* __restrict__ nz_l) {
  int wave = (blockIdx.x * blockDim.x + threadIdx.x) >> 6;
  int lane = threadIdx.x & 63;
  int g = lane >> 4, q = lane & 15;
  int node = wave * 4 + g;
  if (node >= NT) return;
  int beg = row[node], end = row[node + 1];
  float cn = coef[node];
  float sx = 0.f, sy = 0.f, sz = 0.f, sw = 0.f;
  float cA = 0.f, cB = 0.f;
  float4 vA = {0.f, 0.f, 0.f, 0.f}, vB = vA;
  if (beg < end) {
    int m = col[beg];
    cA = coef[m];
    vA = *(const float4*)(in + (size_t)m * DD + q * 4);
  }
  if (beg + 1 < end) {
    int m = col[beg + 1];
    cB = coef[m];
    vB = *(const float4*)(in + (size_t)m * DD + q * 4);
  }
  for (int k = beg; k < end; ++k) {
    float w = cn * cA;          // one rounding (np: cu*ci)
    float4 v = vA;
    cA = cB; vA = vB;
    if (k + 2 < end) {
      int m = col[k + 2];
      cB = coef[m];
      vB = *(const float4*)(in + (size_t)m * DD + q * 4);
    }
    sx = sx + (v.x * w);        // mul then add, per-op rounding, strict order
    sy = sy + (v.y * w);
    sz = sz + (v.z * w);
    sw = sw + (v.w * w);
  }
  // Noise norm, bit-identical: r[j] = sum over k of sq[8k+j] (sequential), tree combine.
  float4 nzv = *(const float4*)(nz_l + (size_t)node * DD + q * 4);
  float4 sq;
  sq.x = nzv.x * nzv.x; sq.y = nzv.y * nzv.y;
  sq.z = nzv.z * nzv.z; sq.w = nzv.w * nzv.w;
  float rA0 = 0.f, rA1 = 0.f, rA2 = 0.f, rA3 = 0.f;
  float rB0 = 0.f, rB1 = 0.f, rB2 = 0.f, rB3 = 0.f;
  int base = g * 16;
#pragma unroll
  for (int k = 0; k < 8; ++k) {
    int le = base + 2 * k, lo = le + 1;
    rA0 = rA0 + __shfl(sq.x, le, 64);
    rA1 = rA1 + __shfl(sq.y, le, 64);
    rA2 = rA2 + __shfl(sq.z, le, 64);
    rA3 = rA3 + __shfl(sq.w, le, 64);
    rB0 = rB0 + __shfl(sq.x, lo, 64);
    rB1 = rB1 + __shfl(sq.y, lo, 64);
    rB2 = rB2 + __shfl(sq.z, lo, 64);
    rB3 = rB3 + __shfl(sq.w, lo, 64);
  }
  float t01 = rA0 + rA1, t23 = rA2 + rA3;
  float t45 = rB0 + rB1, t67 = rB2 + rB3;
  float tot = (t01 + t23) + (t45 + t67);
  float nrm = __fsqrt_rn(tot);
  float den = fmaxf(nrm, 1e-12f);
  float4 o;
  {
    float nn = nzv.x / den;
    float sg = (sx > 0.f) ? 1.f : ((sx < 0.f) ? -1.f : 0.f);
    o.x = sx + ((sg * nn) * 0.2f);
  }
  {
    float nn = nzv.y / den;
    float sg = (sy > 0.f) ? 1.f : ((sy < 0.f) ? -1.f : 0.f);
    o.y = sy + ((sg * nn) * 0.2f);
  }
  {
    float nn = nzv.z / den;
    float sg = (sz > 0.f) ? 1.f : ((sz < 0.f) ? -1.f : 0.f);
    o.z = sz + ((sg * nn) * 0.2f);
  }
  {
    float nn = nzv.w / den;
    float sg = (sw > 0.f) ? 1.f : ((sw < 0.f) ? -1.f : 0.f);
    o.w = sw + ((sg * nn) * 0.2f);
  }
  size_t boff = (size_t)node * DD + q * 4;
  *(float4*)(out + boff) = o;
  float4 a = *(const float4*)(acc + boff);
  a.x = a.x + o.x; a.y = a.y + o.y; a.z = a.z + o.z; a.w = a.w + o.w;
  *(float4*)(acc + boff) = a;
}

__global__ __launch_bounds__(256) void mean_k(const float* __restrict__ acc, float* __restrict__ emb) {
  int idx = blockIdx.x * blockDim.x + threadIdx.x;
  int stride = gridDim.x * blockDim.x;
  for (int j = idx; j < NTD; j += stride) emb[j] = acc[j] * 0.25f;
}

// RF phase 1: s[e] = dot(emb_u, emb_i) once per edge. 4 edges/wave, 16 lanes x float4.
__global__ __launch_bounds__(256) void score_k(const float* __restrict__ emb,
                                               const int* __restrict__ eu, const int* __restrict__ ei,
                                               float* __restrict__ S) {
  int wave = (blockIdx.x * blockDim.x + threadIdx.x) >> 6;
  int lane = threadIdx.x & 63;
  int g = lane >> 4, q = lane & 15;
  int e = wave * 4 + g;
  if (e >= NE) return;
  int u = eu[e];
  int it = NU + ei[e];
  float4 a = *(const float4*)(emb + (size_t)u * DD + q * 4);
  float4 b = *(const float4*)(emb + (size_t)it * DD + q * 4);
  float d = fmaf(a.x, b.x, fmaf(a.y, b.y, fmaf(a.z, b.z, a.w * b.w)));
#pragma unroll
  for (int off = 1; off < 16; off <<= 1) d += __shfl_xor(d, off, 64);
  if (q == 0) S[e] = d;
}

// RF phase 2: per node, m = max s, p[k] = exp(s-m) (unnormalized, CSR order), Zinv = 1/max(sum p,1e-9).
__global__ __launch_bounds__(256) void mz_k(const float* __restrict__ S,
                                            const int* __restrict__ row, const int* __restrict__ seid,
                                            float* __restrict__ P, float* __restrict__ Zinv) {
  int wv = (blockIdx.x * blockDim.x + threadIdx.x) >> 6;
  int lane = threadIdx.x & 63;
  if (wv >= NT) return;
  int beg = row[wv], end = row[wv + 1];
  int n0 = beg + lane;
  float s0 = 0.f;
  float m = -__builtin_inff();
  if (n0 < end) { s0 = S[seid[n0]]; m = s0; }
  for (int idx = n0 + 64; idx < end; idx += 64) m = fmaxf(m, S[seid[idx]]);
#pragma unroll
  for (int off = 1; off < 64; off <<= 1) m = fmaxf(m, __shfl_xor(m, off, 64));
  float zp = 0.f;
  if (n0 < end) { float p = __expf(s0 - m); P[n0] = p; zp = p; }
  for (int idx = n0 + 64; idx < end; idx += 64) {
    float p = __expf(S[seid[idx]] - m);
    P[idx] = p;
    zp += p;
  }
#pragma unroll
  for (int off = 1; off < 64; off <<= 1) zp += __shfl_xor(zp, off, 64);
  if (lane == 0) Zinv[wv] = 1.f / fmaxf(zp, 1e-9f);
}

// RF phase 3: rec = Zinv * sum p*v; out = 0.5*e + 0.5*rec. 4 nodes/wave, depth-2 pipeline.
__global__ __launch_bounds__(256) void accum_k(const float* __restrict__ in, float* __restrict__ out,
                                               const int* __restrict__ row, const int* __restrict__ col,
                                               const float* __restrict__ P, const float* __restrict__ Zinv) {
  int wave = (blockIdx.x * blockDim.x + threadIdx.x) >> 6;
  int lane = threadIdx.x & 63;
  int g = lane >> 4, q = lane & 15;
  int node = wave * 4 + g;
  if (node >= NT) return;
  int beg = row[node], end = row[node + 1];
  float rx = 0.f, ry = 0.f, rz = 0.f, rw = 0.f;
  float pA = 0.f, pB = 0.f;
  float4 vA = {0.f, 0.f, 0.f, 0.f}, vB = vA;
  if (beg < end) {
    pA = P[beg];
    vA = *(const float4*)(in + (size_t)col[beg] * DD + q * 4);
  }
  if (beg + 1 < end) {
    pB = P[beg + 1];
    vB = *(const float4*)(in + (size_t)col[beg + 1] * DD + q * 4);
  }
  for (int k = beg; k < end; ++k) {
    float p = pA;
    float4 v = vA;
    pA = pB; vA = vB;
    if (k + 2 < end) {
      pB = P[k + 2];
      vB = *(const float4*)(in + (size_t)col[k + 2] * DD + q * 4);
    }
    rx = fmaf(p, v.x, rx); ry = fmaf(p, v.y, ry);
    rz = fmaf(p, v.z, rz); rw = fmaf(p, v.w, rw);
  }
  float zi = Zinv[node];
  size_t boff = (size_t)node * DD + q * 4;
  float4 e = *(const float4*)(in + boff);
  float4 o;
  o.x = 0.5f * e.x + 0.5f * (rx * zi);
  o.y = 0.5f * e.y + 0.5f * (ry * zi);
  o.z = 0.5f * e.z + 0.5f * (rz * zi);
  o.w = 0.5f * e.w + 0.5f * (rw * zi);
  *(float4*)(out + boff) = o;
}

extern "C" void kernel_launch(void* const* d_in, const int* in_sizes, int n_in,
                              void* d_out, int out_size, void* d_ws, size_t ws_size,
                              hipStream_t stream) {
  const float* user_emb = (const float*)d_in[0];
  const float* item_emb = (const float*)d_in[1];
  const float* noise    = (const float*)d_in[2];
  const int*   edge_u   = (const int*)d_in[3];
  const int*   edge_i   = (const int*)d_in[4];
  float* out = (float*)d_out;

  // ws layout (~136 MB)
  float* embA = (float*)d_ws;                      // NTD
  float* embB = embA + (size_t)NTD;                // NTD
  float* coef = embB + (size_t)NTD;                // NT+16
  int*   row  = (int*)(coef + (NT + 16));          // NT+16
  int*   cursor = row + (NT + 16);                 // NT+16
  int*   partials = cursor + (NT + 16);            // 256
  int*   eidt = partials + 256;                    // 2E (dead after sort_k -> reused as P)
  int*   col  = eidt + 2 * (size_t)NE;             // 2E
  int*   seid = col + 2 * (size_t)NE;              // 2E
  float* S    = (float*)(seid + 2 * (size_t)NE);   // E
  float* Zinv = S + NE;                            // NT+16
  float* P    = (float*)eidt;                      // 2E (aliases eidt)

  float* acc = out;  // layer-mean accumulator lives in d_out until the final RF pass

  const int nchunks = (NT + 1023) / 1024;

  zero_k<<<(NT + 255) / 256, 256, 0, stream>>>(cursor, NT);
  count_k<<<1024, 256, 0, stream>>>(edge_u, edge_i, cursor);
  scanA_k<<<nchunks, 1024, 0, stream>>>(cursor, row, partials, NT);
  scanB_k<<<1, 64, 0, stream>>>(partials, row, nchunks);
  scanC_k<<<nchunks, 1024, 0, stream>>>(row, cursor, coef, partials, NT);
  fill_k<<<1024, 256, 0, stream>>>(edge_u, edge_i, cursor, eidt);

  const int gwave = (NT * 64 + 255) / 256;   // 64-lane-per-node grids (sort, mz)
  const int g4    = (NT / 4 * 64) / 256;     // 4-node-per-wave grids (gcn4, accum) = 9375
  const int gsc   = (NE / 4 * 64) / 256;     // score grid = 125000

  sort_k<<<gwave, 256, 0, stream>>>(row, eidt, edge_u, edge_i, col, seid);
  init_k<<<4096, 256, 0, stream>>>(user_emb, item_emb, embA, acc);

  float* cur = embA;
  float* nxt = embB;
  for (int layer = 0; layer < 3; ++layer) {
    gcn4_k<<<g4, 256, 0, stream>>>(cur, nxt, acc, row, col, coef,
                                   noise + (size_t)layer * NTD);
    float* t = cur; cur = nxt; nxt = t;
  }
  mean_k<<<4096, 256, 0, stream>>>(acc, embA);

  // RF layer 1: embA -> embB
  score_k<<<gsc, 256, 0, stream>>>(embA, edge_u, edge_i, S);
  mz_k<<<gwave, 256, 0, stream>>>(S, row, seid, P, Zinv);
  accum_k<<<g4, 256, 0, stream>>>(embA, embB, row, col, P, Zinv);
  // RF layer 2: embB -> out
  score_k<<<gsc, 256, 0, stream>>>(embB, edge_u, edge_i, S);
  mz_k<<<gwave, 256, 0, stream>>>(S, row, seid, P, Zinv);
  accum_k<<<g4, 256, 0, stream>>>(embB, out, row, col, P, Zinv);
}

// Round 7
// 1762.235 us; speedup vs baseline: 1.6546x; 1.0081x over previous
//
#include <hip/hip_runtime.h>
#include <math.h>

// Force numpy-style arithmetic: no FMA contraction, no reassociation.
// RF kernels use explicit fmaf() where fusion is wanted (smooth ops).
#pragma clang fp contract(off)
#pragma clang fp reassociate(off)

#define NU 100000
#define NI 50000
#define NT 150000
#define DD 64
#define NE 2000000
#define NTD (NT * DD)
#define NPART 8
#define PARTW (NT / NPART)     // 18750 nodes per XCD partition
#define NCHUNK 256
#define CHW ((NE + NCHUNK - 1) / NCHUNK)   // 7813 edges per chunk

__global__ __launch_bounds__(256) void zero_k(int* __restrict__ p, int n) {
  int i = blockIdx.x * 256 + threadIdx.x;
  if (i < n) p[i] = 0;
}

// XCD-partitioned count: block b scans chunk b>>3, only counts endpoints whose
// destination node is in partition b&7. With blockIdx%8 == XCD, each cnt line is
// touched by exactly one XCD's L2 -> single writeback, local atomics.
__global__ __launch_bounds__(256) void count_k(const int* __restrict__ eu, const int* __restrict__ ei,
                                               int* __restrict__ cnt) {
  int part = blockIdx.x & 7;
  int chunk = blockIdx.x >> 3;
  int lo = part * PARTW, hi = lo + PARTW;
  int e0 = chunk * CHW;
  int e1 = e0 + CHW; if (e1 > NE) e1 = NE;
  for (int e = e0 + threadIdx.x; e < e1; e += 256) {
    int u = eu[e];
    int it = NU + ei[e];
    if (u >= lo && u < hi) atomicAdd(&cnt[u], 1);
    if (it >= lo && it < hi) atomicAdd(&cnt[it], 1);
  }
}

__global__ __launch_bounds__(1024) void scanA_k(const int* __restrict__ cnt, int* __restrict__ lexcl,
                                                int* __restrict__ partials, int n) {
  int idx = blockIdx.x * 1024 + threadIdx.x;
  int v = (idx < n) ? cnt[idx] : 0;
  int lane = threadIdx.x & 63;
  int wid = threadIdx.x >> 6;
  int x = v;
#pragma unroll
  for (int off = 1; off < 64; off <<= 1) {
    int y = __shfl_up(x, off, 64);
    if (lane >= off) x += y;
  }
  __shared__ int wtot[16], woff[16];
  if (lane == 63) wtot[wid] = x;
  __syncthreads();
  if (threadIdx.x == 0) {
    int a = 0;
#pragma unroll
    for (int w = 0; w < 16; ++w) { woff[w] = a; a += wtot[w]; }
    partials[blockIdx.x] = a;
  }
  __syncthreads();
  if (idx < n) lexcl[idx] = x - v + woff[wid];
}

__global__ __launch_bounds__(64) void scanB_k(int* __restrict__ partials, int* __restrict__ row, int nchunks) {
  int lane = threadIdx.x;
  int carry = 0;
  for (int base = 0; base < nchunks; base += 64) {
    int idx = base + lane;
    int v = (idx < nchunks) ? partials[idx] : 0;
    int x = v;
#pragma unroll
    for (int off = 1; off < 64; off <<= 1) {
      int y = __shfl_up(x, off, 64);
      if (lane >= off) x += y;
    }
    if (idx < nchunks) partials[idx] = carry + x - v;
    carry += __shfl(x, 63, 64);
  }
  if (lane == 0) row[NT] = carry;
}

__global__ __launch_bounds__(1024) void scanC_k(int* __restrict__ row, int* __restrict__ cursor,
                                                float* __restrict__ coef, const int* __restrict__ partials, int n) {
  int idx = blockIdx.x * 1024 + threadIdx.x;
  if (idx >= n) return;
  int c = cursor[idx];  // raw count
  int fin = row[idx] + partials[blockIdx.x];
  row[idx] = fin;
  cursor[idx] = fin;
  coef[idx] = (float)pow((double)(c > 0 ? c : 1), -0.5);
}

// XCD-partitioned fill: block b scans chunk b>>3, writes only endpoints in partition b&7.
// eid slots for a node partition are contiguous (row monotone) -> each eid/cursor line is
// written by one XCD only -> no cross-XCD line bouncing (the round-6 15x write amplification).
__global__ __launch_bounds__(256) void fill_k(const int* __restrict__ eu, const int* __restrict__ ei,
                                              int* __restrict__ cursor, int* __restrict__ eid) {
  int part = blockIdx.x & 7;
  int chunk = blockIdx.x >> 3;
  int lo = part * PARTW, hi = lo + PARTW;
  int e0 = chunk * CHW;
  int e1 = e0 + CHW; if (e1 > NE) e1 = NE;
  for (int e = e0 + threadIdx.x; e < e1; e += 256) {
    int u = eu[e];
    int it = NU + ei[e];
    if (u >= lo && u < hi) {
      int p = atomicAdd(&cursor[u], 1);
      eid[p] = e;
    }
    if (it >= lo && it < hi) {
      int p = atomicAdd(&cursor[it], 1);
      eid[p] = e;
    }
  }
}

// Rank-sort each segment by edge id -> col/seid in exact edge order (deterministic).
__global__ __launch_bounds__(256) void sort_k(const int* __restrict__ row, const int* __restrict__ eid,
                                              const int* __restrict__ eu, const int* __restrict__ ei,
                                              int* __restrict__ col, int* __restrict__ seid) {
  int wv = (blockIdx.x * blockDim.x + threadIdx.x) >> 6;
  int lane = threadIdx.x & 63;
  if (wv >= NT) return;
  int beg = row[wv], end = row[wv + 1];
  for (int idx = beg + lane; idx < end; idx += 64) {
    int my = eid[idx];
    int r = 0;
    for (int j = beg; j < end; ++j) r += (eid[j] < my);
    col[beg + r] = (wv < NU) ? (NU + ei[my]) : eu[my];
    seid[beg + r] = my;
  }
}

__global__ __launch_bounds__(256) void init_k(const float* __restrict__ ue, const float* __restrict__ ie,
                                              float* __restrict__ emb, float* __restrict__ acc) {
  int idx = blockIdx.x * blockDim.x + threadIdx.x;
  int stride = gridDim.x * blockDim.x;
  for (int j = idx; j < NTD; j += stride) {
    float v = (j < NU * DD) ? ue[j] : ie[j - NU * DD];
    emb[j] = v;
    acc[j] = v;
  }
}

// GCN layer: 4 nodes/wave, 16 lanes x float4 dims, depth-2 gather pipeline.
// Arithmetic bit-identical to the validated version: per-dim strict edge-order sum,
// separate mul/add rounding; noise pairwise-sum r[j]=sum_k sq[8k+j] + fixed tree.
__global__ __launch_bounds__(256) void gcn4_k(const float* __restrict__ in, float* __restrict__ out,
                                              float* __restrict__ acc,
                                              const int* __restrict__ row, const int* __restrict__ col,
                                              const float* __restrict__ coef, const float* __restrict__ nz_l) {
  int wave = (blockIdx.x * blockDim.x + threadIdx.x) >> 6;
  int lane = threadIdx.x & 63;
  int g = lane >> 4, q = lane & 15;
  int node = wave * 4 + g;
  if (node >= NT) return;
  int beg = row[node], end = row[node + 1];
  float cn = coef[node];
  float sx = 0.f, sy = 0.f, sz = 0.f, sw = 0.f;
  float cA = 0.f, cB = 0.f;
  float4 vA = {0.f, 0.f, 0.f, 0.f}, vB = vA;
  if (beg < end) {
    int m = col[beg];
    cA = coef[m];
    vA = *(const float4*)(in + (size_t)m * DD + q * 4);
  }
  if (beg + 1 < end) {
    int m = col[beg + 1];
    cB = coef[m];
    vB = *(const float4*)(in + (size_t)m * DD + q * 4);
  }
  for (int k = beg; k < end; ++k) {
    float w = cn * cA;          // one rounding (np: cu*ci)
    float4 v = vA;
    cA = cB; vA = vB;
    if (k + 2 < end) {
      int m = col[k + 2];
      cB = coef[m];
      vB = *(const float4*)(in + (size_t)m * DD + q * 4);
    }
    sx = sx + (v.x * w);        // mul then add, per-op rounding, strict order
    sy = sy + (v.y * w);
    sz = sz + (v.z * w);
    sw = sw + (v.w * w);
  }
  // Noise norm, bit-identical: r[j] = sum over k of sq[8k+j] (sequential), tree combine.
  float4 nzv = *(const float4*)(nz_l + (size_t)node * DD + q * 4);
  float4 sq;
  sq.x = nzv.x * nzv.x; sq.y = nzv.y * nzv.y;
  sq.z = nzv.z * nzv.z; sq.w = nzv.w * nzv.w;
  float rA0 = 0.f, rA1 = 0.f, rA2 = 0.f, rA3 = 0.f;
  float rB0 = 0.f, rB1 = 0.f, rB2 = 0.f, rB3 = 0.f;
  int base = g * 16;
#pragma unroll
  for (int k = 0; k < 8; ++k) {
    int le = base + 2 * k, lo = le + 1;
    rA0 = rA0 + __shfl(sq.x, le, 64);
    rA1 = rA1 + __shfl(sq.y, le, 64);
    rA2 = rA2 + __shfl(sq.z, le, 64);
    rA3 = rA3 + __shfl(sq.w, le, 64);
    rB0 = rB0 + __shfl(sq.x, lo, 64);
    rB1 = rB1 + __shfl(sq.y, lo, 64);
    rB2 = rB2 + __shfl(sq.z, lo, 64);
    rB3 = rB3 + __shfl(sq.w, lo, 64);
  }
  float t01 = rA0 + rA1, t23 = rA2 + rA3;
  float t45 = rB0 + rB1, t67 = rB2 + rB3;
  float tot = (t01 + t23) + (t45 + t67);
  float nrm = __fsqrt_rn(tot);
  float den = fmaxf(nrm, 1e-12f);
  float4 o;
  {
    float nn = nzv.x / den;
    float sg = (sx > 0.f) ? 1.f : ((sx < 0.f) ? -1.f : 0.f);
    o.x = sx + ((sg * nn) * 0.2f);
  }
  {
    float nn = nzv.y / den;
    float sg = (sy > 0.f) ? 1.f : ((sy < 0.f) ? -1.f : 0.f);
    o.y = sy + ((sg * nn) * 0.2f);
  }
  {
    float nn = nzv.z / den;
    float sg = (sz > 0.f) ? 1.f : ((sz < 0.f) ? -1.f : 0.f);
    o.z = sz + ((sg * nn) * 0.2f);
  }
  {
    float nn = nzv.w / den;
    float sg = (sw > 0.f) ? 1.f : ((sw < 0.f) ? -1.f : 0.f);
    o.w = sw + ((sg * nn) * 0.2f);
  }
  size_t boff = (size_t)node * DD + q * 4;
  *(float4*)(out + boff) = o;
  float4 a = *(const float4*)(acc + boff);
  a.x = a.x + o.x; a.y = a.y + o.y; a.z = a.z + o.z; a.w = a.w + o.w;
  *(float4*)(acc + boff) = a;
}

__global__ __launch_bounds__(256) void mean_k(const float* __restrict__ acc, float* __restrict__ emb) {
  int idx = blockIdx.x * blockDim.x + threadIdx.x;
  int stride = gridDim.x * blockDim.x;
  for (int j = idx; j < NTD; j += stride) emb[j] = acc[j] * 0.25f;
}

// RF phase 1: s[e] = dot(emb_u, emb_i) once per edge. 4 edges/wave, 16 lanes x float4.
__global__ __launch_bounds__(256) void score_k(const float* __restrict__ emb,
                                               const int* __restrict__ eu, const int* __restrict__ ei,
                                               float* __restrict__ S) {
  int wave = (blockIdx.x * blockDim.x + threadIdx.x) >> 6;
  int lane = threadIdx.x & 63;
  int g = lane >> 4, q = lane & 15;
  int e = wave * 4 + g;
  if (e >= NE) return;
  int u = eu[e];
  int it = NU + ei[e];
  float4 a = *(const float4*)(emb + (size_t)u * DD + q * 4);
  float4 b = *(const float4*)(emb + (size_t)it * DD + q * 4);
  float d = fmaf(a.x, b.x, fmaf(a.y, b.y, fmaf(a.z, b.z, a.w * b.w)));
#pragma unroll
  for (int off = 1; off < 16; off <<= 1) d += __shfl_xor(d, off, 64);
  if (q == 0) S[e] = d;
}

// RF phase 2: per node, m = max s, p[k] = exp(s-m) (unnormalized, CSR order), Zinv = 1/max(sum p,1e-9).
__global__ __launch_bounds__(256) void mz_k(const float* __restrict__ S,
                                            const int* __restrict__ row, const int* __restrict__ seid,
                                            float* __restrict__ P, float* __restrict__ Zinv) {
  int wv = (blockIdx.x * blockDim.x + threadIdx.x) >> 6;
  int lane = threadIdx.x & 63;
  if (wv >= NT) return;
  int beg = row[wv], end = row[wv + 1];
  int n0 = beg + lane;
  float s0 = 0.f;
  float m = -__builtin_inff();
  if (n0 < end) { s0 = S[seid[n0]]; m = s0; }
  for (int idx = n0 + 64; idx < end; idx += 64) m = fmaxf(m, S[seid[idx]]);
#pragma unroll
  for (int off = 1; off < 64; off <<= 1) m = fmaxf(m, __shfl_xor(m, off, 64));
  float zp = 0.f;
  if (n0 < end) { float p = __expf(s0 - m); P[n0] = p; zp = p; }
  for (int idx = n0 + 64; idx < end; idx += 64) {
    float p = __expf(S[seid[idx]] - m);
    P[idx] = p;
    zp += p;
  }
#pragma unroll
  for (int off = 1; off < 64; off <<= 1) zp += __shfl_xor(zp, off, 64);
  if (lane == 0) Zinv[wv] = 1.f / fmaxf(zp, 1e-9f);
}

// RF phase 3: rec = Zinv * sum p*v; out = 0.5*e + 0.5*rec. 4 nodes/wave, depth-2 pipeline.
__global__ __launch_bounds__(256) void accum_k(const float* __restrict__ in, float* __restrict__ out,
                                               const int* __restrict__ row, const int* __restrict__ col,
                                               const float* __restrict__ P, const float* __restrict__ Zinv) {
  int wave = (blockIdx.x * blockDim.x + threadIdx.x) >> 6;
  int lane = threadIdx.x & 63;
  int g = lane >> 4, q = lane & 15;
  int node = wave * 4 + g;
  if (node >= NT) return;
  int beg = row[node], end = row[node + 1];
  float rx = 0.f, ry = 0.f, rz = 0.f, rw = 0.f;
  float pA = 0.f, pB = 0.f;
  float4 vA = {0.f, 0.f, 0.f, 0.f}, vB = vA;
  if (beg < end) {
    pA = P[beg];
    vA = *(const float4*)(in + (size_t)col[beg] * DD + q * 4);
  }
  if (beg + 1 < end) {
    pB = P[beg + 1];
    vB = *(const float4*)(in + (size_t)col[beg + 1] * DD + q * 4);
  }
  for (int k = beg; k < end; ++k) {
    float p = pA;
    float4 v = vA;
    pA = pB; vA = vB;
    if (k + 2 < end) {
      pB = P[k + 2];
      vB = *(const float4*)(in + (size_t)col[k + 2] * DD + q * 4);
    }
    rx = fmaf(p, v.x, rx); ry = fmaf(p, v.y, ry);
    rz = fmaf(p, v.z, rz); rw = fmaf(p, v.w, rw);
  }
  float zi = Zinv[node];
  size_t boff = (size_t)node * DD + q * 4;
  float4 e = *(const float4*)(in + boff);
  float4 o;
  o.x = 0.5f * e.x + 0.5f * (rx * zi);
  o.y = 0.5f * e.y + 0.5f * (ry * zi);
  o.z = 0.5f * e.z + 0.5f * (rz * zi);
  o.w = 0.5f * e.w + 0.5f * (rw * zi);
  *(float4*)(out + boff) = o;
}

extern "C" void kernel_launch(void* const* d_in, const int* in_sizes, int n_in,
                              void* d_out, int out_size, void* d_ws, size_t ws_size,
                              hipStream_t stream) {
  const float* user_emb = (const float*)d_in[0];
  const float* item_emb = (const float*)d_in[1];
  const float* noise    = (const float*)d_in[2];
  const int*   edge_u   = (const int*)d_in[3];
  const int*   edge_i   = (const int*)d_in[4];
  float* out = (float*)d_out;

  // ws layout (~136 MB)
  float* embA = (float*)d_ws;                      // NTD
  float* embB = embA + (size_t)NTD;                // NTD
  float* coef = embB + (size_t)NTD;                // NT+16
  int*   row  = (int*)(coef + (NT + 16));          // NT+16
  int*   cursor = row + (NT + 16);                 // NT+16
  int*   partials = cursor + (NT + 16);            // 256
  int*   eidt = partials + 256;                    // 2E (dead after sort_k -> reused as P)
  int*   col  = eidt + 2 * (size_t)NE;             // 2E
  int*   seid = col + 2 * (size_t)NE;              // 2E
  float* S    = (float*)(seid + 2 * (size_t)NE);   // E
  float* Zinv = S + NE;                            // NT+16
  float* P    = (float*)eidt;                      // 2E (aliases eidt)

  float* acc = out;  // layer-mean accumulator lives in d_out until the final RF pass

  const int nchunks = (NT + 1023) / 1024;

  zero_k<<<(NT + 255) / 256, 256, 0, stream>>>(cursor, NT);
  count_k<<<NCHUNK * NPART, 256, 0, stream>>>(edge_u, edge_i, cursor);
  scanA_k<<<nchunks, 1024, 0, stream>>>(cursor, row, partials, NT);
  scanB_k<<<1, 64, 0, stream>>>(partials, row, nchunks);
  scanC_k<<<nchunks, 1024, 0, stream>>>(row, cursor, coef, partials, NT);
  fill_k<<<NCHUNK * NPART, 256, 0, stream>>>(edge_u, edge_i, cursor, eidt);

  const int gwave = (NT * 64 + 255) / 256;   // 64-lane-per-node grids (sort, mz)
  const int g4    = (NT / 4 * 64) / 256;     // 4-node-per-wave grids (gcn4, accum) = 9375
  const int gsc   = (NE / 4 * 64) / 256;     // score grid = 125000

  sort_k<<<gwave, 256, 0, stream>>>(row, eidt, edge_u, edge_i, col, seid);
  init_k<<<4096, 256, 0, stream>>>(user_emb, item_emb, embA, acc);

  float* cur = embA;
  float* nxt = embB;
  for (int layer = 0; layer < 3; ++layer) {
    gcn4_k<<<g4, 256, 0, stream>>>(cur, nxt, acc, row, col, coef,
                                   noise + (size_t)layer * NTD);
    float* t = cur; cur = nxt; nxt = t;
  }
  mean_k<<<4096, 256, 0, stream>>>(acc, embA);

  // RF layer 1: embA -> embB
  score_k<<<gsc, 256, 0, stream>>>(embA, edge_u, edge_i, S);
  mz_k<<<gwave, 256, 0, stream>>>(S, row, seid, P, Zinv);
  accum_k<<<g4, 256, 0, stream>>>(embA, embB, row, col, P, Zinv);
  // RF layer 2: embB -> out
  score_k<<<gsc, 256, 0, stream>>>(embB, edge_u, edge_i, S);
  mz_k<<<gwave, 256, 0, stream>>>(S, row, seid, P, Zinv);
  accum_k<<<g4, 256, 0, stream>>>(embB, out, row, col, P, Zinv);
}

// Round 8
// 1551.203 us; speedup vs baseline: 1.8797x; 1.1360x over previous
//
#include <hip/hip_runtime.h>
#include <math.h>

// Force numpy-style arithmetic: no FMA contraction, no reassociation.
// RF kernels use explicit fmaf() where fusion is wanted (smooth ops).
#pragma clang fp contract(off)
#pragma clang fp reassociate(off)

#define NU 100000
#define NI 50000
#define NT 150000
#define DD 64
#define NE 2000000
#define NTD (NT * DD)
#define NPART 8
#define PARTW (NT / NPART)     // 18750 nodes per XCD partition
#define NCHUNK 256
#define CHW ((NE + NCHUNK - 1) / NCHUNK)   // 7813 edges per chunk

__global__ __launch_bounds__(256) void zero_k(int* __restrict__ p, int n) {
  int i = blockIdx.x * 256 + threadIdx.x;
  if (i < n) p[i] = 0;
}

// XCD-partitioned count: block b scans chunk b>>3, only counts endpoints whose
// destination node is in partition b&7 (one XCD's L2 owns each cnt line).
__global__ __launch_bounds__(256) void count_k(const int* __restrict__ eu, const int* __restrict__ ei,
                                               int* __restrict__ cnt) {
  int part = blockIdx.x & 7;
  int chunk = blockIdx.x >> 3;
  int lo = part * PARTW, hi = lo + PARTW;
  int e0 = chunk * CHW;
  int e1 = e0 + CHW; if (e1 > NE) e1 = NE;
  for (int e = e0 + threadIdx.x; e < e1; e += 256) {
    int u = eu[e];
    int it = NU + ei[e];
    if (u >= lo && u < hi) atomicAdd(&cnt[u], 1);
    if (it >= lo && it < hi) atomicAdd(&cnt[it], 1);
  }
}

__global__ __launch_bounds__(1024) void scanA_k(const int* __restrict__ cnt, int* __restrict__ lexcl,
                                                int* __restrict__ partials, int n) {
  int idx = blockIdx.x * 1024 + threadIdx.x;
  int v = (idx < n) ? cnt[idx] : 0;
  int lane = threadIdx.x & 63;
  int wid = threadIdx.x >> 6;
  int x = v;
#pragma unroll
  for (int off = 1; off < 64; off <<= 1) {
    int y = __shfl_up(x, off, 64);
    if (lane >= off) x += y;
  }
  __shared__ int wtot[16], woff[16];
  if (lane == 63) wtot[wid] = x;
  __syncthreads();
  if (threadIdx.x == 0) {
    int a = 0;
#pragma unroll
    for (int w = 0; w < 16; ++w) { woff[w] = a; a += wtot[w]; }
    partials[blockIdx.x] = a;
  }
  __syncthreads();
  if (idx < n) lexcl[idx] = x - v + woff[wid];
}

__global__ __launch_bounds__(64) void scanB_k(int* __restrict__ partials, int* __restrict__ row, int nchunks) {
  int lane = threadIdx.x;
  int carry = 0;
  for (int base = 0; base < nchunks; base += 64) {
    int idx = base + lane;
    int v = (idx < nchunks) ? partials[idx] : 0;
    int x = v;
#pragma unroll
    for (int off = 1; off < 64; off <<= 1) {
      int y = __shfl_up(x, off, 64);
      if (lane >= off) x += y;
    }
    if (idx < nchunks) partials[idx] = carry + x - v;
    carry += __shfl(x, 63, 64);
  }
  if (lane == 0) row[NT] = carry;
}

__global__ __launch_bounds__(1024) void scanC_k(int* __restrict__ row, int* __restrict__ cursor,
                                                float* __restrict__ coef, const int* __restrict__ partials, int n) {
  int idx = blockIdx.x * 1024 + threadIdx.x;
  if (idx >= n) return;
  int c = cursor[idx];  // raw count
  int fin = row[idx] + partials[blockIdx.x];
  row[idx] = fin;
  cursor[idx] = fin;
  coef[idx] = (float)pow((double)(c > 0 ? c : 1), -0.5);
}

// XCD-partitioned fill (round-7 win): each eid/cursor line written by one XCD only.
__global__ __launch_bounds__(256) void fill_k(const int* __restrict__ eu, const int* __restrict__ ei,
                                              int* __restrict__ cursor, int* __restrict__ eid) {
  int part = blockIdx.x & 7;
  int chunk = blockIdx.x >> 3;
  int lo = part * PARTW, hi = lo + PARTW;
  int e0 = chunk * CHW;
  int e1 = e0 + CHW; if (e1 > NE) e1 = NE;
  for (int e = e0 + threadIdx.x; e < e1; e += 256) {
    int u = eu[e];
    int it = NU + ei[e];
    if (u >= lo && u < hi) {
      int p = atomicAdd(&cursor[u], 1);
      eid[p] = e;
    }
    if (it >= lo && it < hi) {
      int p = atomicAdd(&cursor[it], 1);
      eid[p] = e;
    }
  }
}

// Rank-sort each segment by edge id -> col/seid in exact edge order (deterministic).
__global__ __launch_bounds__(256) void sort_k(const int* __restrict__ row, const int* __restrict__ eid,
                                              const int* __restrict__ eu, const int* __restrict__ ei,
                                              int* __restrict__ col, int* __restrict__ seid) {
  int wv = (blockIdx.x * blockDim.x + threadIdx.x) >> 6;
  int lane = threadIdx.x & 63;
  if (wv >= NT) return;
  int beg = row[wv], end = row[wv + 1];
  for (int idx = beg + lane; idx < end; idx += 64) {
    int my = eid[idx];
    int r = 0;
    for (int j = beg; j < end; ++j) r += (eid[j] < my);
    col[beg + r] = (wv < NU) ? (NU + ei[my]) : eu[my];
    seid[beg + r] = my;
  }
}

__global__ __launch_bounds__(256) void init_k(const float* __restrict__ ue, const float* __restrict__ ie,
                                              float* __restrict__ emb, float* __restrict__ acc) {
  int idx = blockIdx.x * blockDim.x + threadIdx.x;
  int stride = gridDim.x * blockDim.x;
  for (int j = idx; j < NTD; j += stride) {
    float v = (j < NU * DD) ? ue[j] : ie[j - NU * DD];
    emb[j] = v;
    acc[j] = v;
  }
}

// GCN layer: 4 nodes/wave, 16 lanes x float4 dims, depth-4+4 chunked gather pipeline
// (8 row-loads in flight per node group). Arithmetic bit-identical: per-dim strict
// edge-order sum, separate mul/add rounding; noise pairwise-sum + fixed tree.
// LAST=1 fuses the layer mean: writes (acc+o)*0.25 to out, skips acc/out updates.
template <int LAST>
__global__ __launch_bounds__(256) void gcn4_k(const float* __restrict__ in, float* __restrict__ out,
                                              float* __restrict__ acc,
                                              const int* __restrict__ row, const int* __restrict__ col,
                                              const float* __restrict__ coef, const float* __restrict__ nz_l) {
  int wave = (blockIdx.x * blockDim.x + threadIdx.x) >> 6;
  int lane = threadIdx.x & 63;
  int g = lane >> 4, q = lane & 15;
  int node = wave * 4 + g;
  if (node >= NT) return;
  int beg = row[node], end = row[node + 1];
  float cn = coef[node];
  float sx = 0.f, sy = 0.f, sz = 0.f, sw = 0.f;

#define GLD(dv, dc, kk) { int m_ = col[kk]; dc = coef[m_]; dv = *(const float4*)(in + (size_t)m_ * DD + q * 4); }
  float4 cv0, cv1, cv2, cv3;
  float cc0, cc1, cc2, cc3;
  int rem = end - beg;
  int k4end = end - (rem & 3);
  int k = beg;
  if (k < k4end) {
    GLD(cv0, cc0, k) GLD(cv1, cc1, k + 1) GLD(cv2, cc2, k + 2) GLD(cv3, cc3, k + 3)
  }
  for (; k < k4end; k += 4) {
    float4 nv0, nv1, nv2, nv3;
    float nc0, nc1, nc2, nc3;
    bool more = (k + 4) < k4end;
    if (more) {
      GLD(nv0, nc0, k + 4) GLD(nv1, nc1, k + 5) GLD(nv2, nc2, k + 6) GLD(nv3, nc3, k + 7)
    }
    // strict order accumulation, per-op rounding
    {
      float w = cn * cc0;
      sx = sx + (cv0.x * w); sy = sy + (cv0.y * w); sz = sz + (cv0.z * w); sw = sw + (cv0.w * w);
    }
    {
      float w = cn * cc1;
      sx = sx + (cv1.x * w); sy = sy + (cv1.y * w); sz = sz + (cv1.z * w); sw = sw + (cv1.w * w);
    }
    {
      float w = cn * cc2;
      sx = sx + (cv2.x * w); sy = sy + (cv2.y * w); sz = sz + (cv2.z * w); sw = sw + (cv2.w * w);
    }
    {
      float w = cn * cc3;
      sx = sx + (cv3.x * w); sy = sy + (cv3.y * w); sz = sz + (cv3.z * w); sw = sw + (cv3.w * w);
    }
    if (more) {
      cv0 = nv0; cc0 = nc0; cv1 = nv1; cc1 = nc1;
      cv2 = nv2; cc2 = nc2; cv3 = nv3; cc3 = nc3;
    }
  }
  for (; k < end; ++k) {  // tail <= 3
    float4 v; float c;
    GLD(v, c, k)
    float w = cn * c;
    sx = sx + (v.x * w); sy = sy + (v.y * w); sz = sz + (v.z * w); sw = sw + (v.w * w);
  }
#undef GLD

  // Noise norm, bit-identical: r[j] = sum over k of sq[8k+j] (sequential), tree combine.
  float4 nzv = *(const float4*)(nz_l + (size_t)node * DD + q * 4);
  float4 sq;
  sq.x = nzv.x * nzv.x; sq.y = nzv.y * nzv.y;
  sq.z = nzv.z * nzv.z; sq.w = nzv.w * nzv.w;
  float rA0 = 0.f, rA1 = 0.f, rA2 = 0.f, rA3 = 0.f;
  float rB0 = 0.f, rB1 = 0.f, rB2 = 0.f, rB3 = 0.f;
  int base = g * 16;
#pragma unroll
  for (int kk = 0; kk < 8; ++kk) {
    int le = base + 2 * kk, lo = le + 1;
    rA0 = rA0 + __shfl(sq.x, le, 64);
    rA1 = rA1 + __shfl(sq.y, le, 64);
    rA2 = rA2 + __shfl(sq.z, le, 64);
    rA3 = rA3 + __shfl(sq.w, le, 64);
    rB0 = rB0 + __shfl(sq.x, lo, 64);
    rB1 = rB1 + __shfl(sq.y, lo, 64);
    rB2 = rB2 + __shfl(sq.z, lo, 64);
    rB3 = rB3 + __shfl(sq.w, lo, 64);
  }
  float t01 = rA0 + rA1, t23 = rA2 + rA3;
  float t45 = rB0 + rB1, t67 = rB2 + rB3;
  float tot = (t01 + t23) + (t45 + t67);
  float nrm = __fsqrt_rn(tot);
  float den = fmaxf(nrm, 1e-12f);
  float4 o;
  {
    float nn = nzv.x / den;
    float sg = (sx > 0.f) ? 1.f : ((sx < 0.f) ? -1.f : 0.f);
    o.x = sx + ((sg * nn) * 0.2f);
  }
  {
    float nn = nzv.y / den;
    float sg = (sy > 0.f) ? 1.f : ((sy < 0.f) ? -1.f : 0.f);
    o.y = sy + ((sg * nn) * 0.2f);
  }
  {
    float nn = nzv.z / den;
    float sg = (sz > 0.f) ? 1.f : ((sz < 0.f) ? -1.f : 0.f);
    o.z = sz + ((sg * nn) * 0.2f);
  }
  {
    float nn = nzv.w / den;
    float sg = (sw > 0.f) ? 1.f : ((sw < 0.f) ? -1.f : 0.f);
    o.w = sw + ((sg * nn) * 0.2f);
  }
  size_t boff = (size_t)node * DD + q * 4;
  float4 a = *(const float4*)(acc + boff);
  if (LAST) {
    // fused mean: fin = acc + o (same rounding as acc update), then *0.25 (exact)
    float4 mo;
    mo.x = (a.x + o.x) * 0.25f;
    mo.y = (a.y + o.y) * 0.25f;
    mo.z = (a.z + o.z) * 0.25f;
    mo.w = (a.w + o.w) * 0.25f;
    *(float4*)(out + boff) = mo;
  } else {
    *(float4*)(out + boff) = o;
    a.x = a.x + o.x; a.y = a.y + o.y; a.z = a.z + o.z; a.w = a.w + o.w;
    *(float4*)(acc + boff) = a;
  }
}

// RF phase 1: s[e] = dot(emb_u, emb_i) once per edge. 4 edges/wave, 16 lanes x float4.
__global__ __launch_bounds__(256) void score_k(const float* __restrict__ emb,
                                               const int* __restrict__ eu, const int* __restrict__ ei,
                                               float* __restrict__ S) {
  int wave = (blockIdx.x * blockDim.x + threadIdx.x) >> 6;
  int lane = threadIdx.x & 63;
  int g = lane >> 4, q = lane & 15;
  int e = wave * 4 + g;
  if (e >= NE) return;
  int u = eu[e];
  int it = NU + ei[e];
  float4 a = *(const float4*)(emb + (size_t)u * DD + q * 4);
  float4 b = *(const float4*)(emb + (size_t)it * DD + q * 4);
  float d = fmaf(a.x, b.x, fmaf(a.y, b.y, fmaf(a.z, b.z, a.w * b.w)));
#pragma unroll
  for (int off = 1; off < 16; off <<= 1) d += __shfl_xor(d, off, 64);
  if (q == 0) S[e] = d;
}

// RF phase 2: per node, m = max s, p[k] = exp(s-m) (unnormalized, CSR order), Zinv = 1/max(sum p,1e-9).
__global__ __launch_bounds__(256) void mz_k(const float* __restrict__ S,
                                            const int* __restrict__ row, const int* __restrict__ seid,
                                            float* __restrict__ P, float* __restrict__ Zinv) {
  int wv = (blockIdx.x * blockDim.x + threadIdx.x) >> 6;
  int lane = threadIdx.x & 63;
  if (wv >= NT) return;
  int beg = row[wv], end = row[wv + 1];
  int n0 = beg + lane;
  float s0 = 0.f;
  float m = -__builtin_inff();
  if (n0 < end) { s0 = S[seid[n0]]; m = s0; }
  for (int idx = n0 + 64; idx < end; idx += 64) m = fmaxf(m, S[seid[idx]]);
#pragma unroll
  for (int off = 1; off < 64; off <<= 1) m = fmaxf(m, __shfl_xor(m, off, 64));
  float zp = 0.f;
  if (n0 < end) { float p = __expf(s0 - m); P[n0] = p; zp = p; }
  for (int idx = n0 + 64; idx < end; idx += 64) {
    float p = __expf(S[seid[idx]] - m);
    P[idx] = p;
    zp += p;
  }
#pragma unroll
  for (int off = 1; off < 64; off <<= 1) zp += __shfl_xor(zp, off, 64);
  if (lane == 0) Zinv[wv] = 1.f / fmaxf(zp, 1e-9f);
}

// RF phase 3: rec = Zinv * sum p*v; out = 0.5*e + 0.5*rec. 4 nodes/wave, depth-4+4 pipeline.
__global__ __launch_bounds__(256) void accum_k(const float* __restrict__ in, float* __restrict__ out,
                                               const int* __restrict__ row, const int* __restrict__ col,
                                               const float* __restrict__ P, const float* __restrict__ Zinv) {
  int wave = (blockIdx.x * blockDim.x + threadIdx.x) >> 6;
  int lane = threadIdx.x & 63;
  int g = lane >> 4, q = lane & 15;
  int node = wave * 4 + g;
  if (node >= NT) return;
  int beg = row[node], end = row[node + 1];
  float rx = 0.f, ry = 0.f, rz = 0.f, rw = 0.f;

#define PLD(dv, dp, kk) { dp = P[kk]; dv = *(const float4*)(in + (size_t)col[kk] * DD + q * 4); }
  float4 cv0, cv1, cv2, cv3;
  float cp0, cp1, cp2, cp3;
  int rem = end - beg;
  int k4end = end - (rem & 3);
  int k = beg;
  if (k < k4end) {
    PLD(cv0, cp0, k) PLD(cv1, cp1, k + 1) PLD(cv2, cp2, k + 2) PLD(cv3, cp3, k + 3)
  }
  for (; k < k4end; k += 4) {
    float4 nv0, nv1, nv2, nv3;
    float np0, np1, np2, np3;
    bool more = (k + 4) < k4end;
    if (more) {
      PLD(nv0, np0, k + 4) PLD(nv1, np1, k + 5) PLD(nv2, np2, k + 6) PLD(nv3, np3, k + 7)
    }
    rx = fmaf(cp0, cv0.x, rx); ry = fmaf(cp0, cv0.y, ry); rz = fmaf(cp0, cv0.z, rz); rw = fmaf(cp0, cv0.w, rw);
    rx = fmaf(cp1, cv1.x, rx); ry = fmaf(cp1, cv1.y, ry); rz = fmaf(cp1, cv1.z, rz); rw = fmaf(cp1, cv1.w, rw);
    rx = fmaf(cp2, cv2.x, rx); ry = fmaf(cp2, cv2.y, ry); rz = fmaf(cp2, cv2.z, rz); rw = fmaf(cp2, cv2.w, rw);
    rx = fmaf(cp3, cv3.x, rx); ry = fmaf(cp3, cv3.y, ry); rz = fmaf(cp3, cv3.z, rz); rw = fmaf(cp3, cv3.w, rw);
    if (more) {
      cv0 = nv0; cp0 = np0; cv1 = nv1; cp1 = np1;
      cv2 = nv2; cp2 = np2; cv3 = nv3; cp3 = np3;
    }
  }
  for (; k < end; ++k) {
    float4 v; float p;
    PLD(v, p, k)
    rx = fmaf(p, v.x, rx); ry = fmaf(p, v.y, ry); rz = fmaf(p, v.z, rz); rw = fmaf(p, v.w, rw);
  }
#undef PLD

  float zi = Zinv[node];
  size_t boff = (size_t)node * DD + q * 4;
  float4 e = *(const float4*)(in + boff);
  float4 o;
  o.x = 0.5f * e.x + 0.5f * (rx * zi);
  o.y = 0.5f * e.y + 0.5f * (ry * zi);
  o.z = 0.5f * e.z + 0.5f * (rz * zi);
  o.w = 0.5f * e.w + 0.5f * (rw * zi);
  *(float4*)(out + boff) = o;
}

extern "C" void kernel_launch(void* const* d_in, const int* in_sizes, int n_in,
                              void* d_out, int out_size, void* d_ws, size_t ws_size,
                              hipStream_t stream) {
  const float* user_emb = (const float*)d_in[0];
  const float* item_emb = (const float*)d_in[1];
  const float* noise    = (const float*)d_in[2];
  const int*   edge_u   = (const int*)d_in[3];
  const int*   edge_i   = (const int*)d_in[4];
  float* out = (float*)d_out;

  // ws layout (~136 MB)
  float* embA = (float*)d_ws;                      // NTD
  float* embB = embA + (size_t)NTD;                // NTD
  float* coef = embB + (size_t)NTD;                // NT+16
  int*   row  = (int*)(coef + (NT + 16));          // NT+16
  int*   cursor = row + (NT + 16);                 // NT+16
  int*   partials = cursor + (NT + 16);            // 256
  int*   eidt = partials + 256;                    // 2E (dead after sort_k -> reused as P)
  int*   col  = eidt + 2 * (size_t)NE;             // 2E
  int*   seid = col + 2 * (size_t)NE;              // 2E
  float* S    = (float*)(seid + 2 * (size_t)NE);   // E
  float* Zinv = S + NE;                            // NT+16
  float* P    = (float*)eidt;                      // 2E (aliases eidt)

  float* acc = out;  // layer-mean accumulator lives in d_out until the final RF pass

  const int nchunks = (NT + 1023) / 1024;

  zero_k<<<(NT + 255) / 256, 256, 0, stream>>>(cursor, NT);
  count_k<<<NCHUNK * NPART, 256, 0, stream>>>(edge_u, edge_i, cursor);
  scanA_k<<<nchunks, 1024, 0, stream>>>(cursor, row, partials, NT);
  scanB_k<<<1, 64, 0, stream>>>(partials, row, nchunks);
  scanC_k<<<nchunks, 1024, 0, stream>>>(row, cursor, coef, partials, NT);
  fill_k<<<NCHUNK * NPART, 256, 0, stream>>>(edge_u, edge_i, cursor, eidt);

  const int gwave = (NT * 64 + 255) / 256;   // 64-lane-per-node grids (sort, mz)
  const int g4    = (NT / 4 * 64) / 256;     // 4-node-per-wave grids (gcn4, accum) = 9375
  const int gsc   = (NE / 4 * 64) / 256;     // score grid = 125000

  sort_k<<<gwave, 256, 0, stream>>>(row, eidt, edge_u, edge_i, col, seid);
  init_k<<<4096, 256, 0, stream>>>(user_emb, item_emb, embA, acc);

  // L0: embA -> embB ; L1: embB -> embA ; L2(last, fused mean): embA -> embB
  gcn4_k<0><<<g4, 256, 0, stream>>>(embA, embB, acc, row, col, coef, noise + 0 * (size_t)NTD);
  gcn4_k<0><<<g4, 256, 0, stream>>>(embB, embA, acc, row, col, coef, noise + 1 * (size_t)NTD);
  gcn4_k<1><<<g4, 256, 0, stream>>>(embA, embB, acc, row, col, coef, noise + 2 * (size_t)NTD);

  // RF layer 1: embB -> embA
  score_k<<<gsc, 256, 0, stream>>>(embB, edge_u, edge_i, S);
  mz_k<<<gwave, 256, 0, stream>>>(S, row, seid, P, Zinv);
  accum_k<<<g4, 256, 0, stream>>>(embB, embA, row, col, P, Zinv);
  // RF layer 2: embA -> out
  score_k<<<gsc, 256, 0, stream>>>(embA, edge_u, edge_i, S);
  mz_k<<<gwave, 256, 0, stream>>>(S, row, seid, P, Zinv);
  accum_k<<<g4, 256, 0, stream>>>(embA, out, row, col, P, Zinv);
}